// Round 8
// baseline (2040.796 us; speedup 1.0000x reference)
//
#include <hip/hip_runtime.h>

// PathEncoder: B=8, N_NODE=512, N_TOK=8, N_PATHS=256, PATH_LEN=64, VOCAB=50000, H=256
// Round 8: 16-wave (1024-thr) scan so the whh weight array needs only 96
// regs/lane (24 x short8) -- fits INSIDE the 128-reg cap that a 1024-thread
// block imposes by hardware (4 waves/SIMD x 128 = 512-reg pool). No more
// fighting the allocator: wave w owns 16 gate-cols per gate; acc[3] = 12 regs.
// xw tables split into RZ (u32/col) + N (u16/col) planes for cheap gathers.
//
// ws layout (bytes), total ~169.9 MB:
//   x       @ 0          4,194,304   [4096][256] f32
//   xwRZ    @ 4194304    8,390,656   [4097*2 rows][256 cols] u32 {r|z<<16}
//   xwN     @ 12584960   4,195,328   [4097*2 rows][256 cols] u16 {n}
//   whhp    @ 16780288     786,432   packed whh bf16 B-frags: chunk ((dir*16+w)*8+kt)*3+g
//   wih_bt  @ 17566720     786,432   [1536][256] bf16 concat(wf_ih, wb_ih)
//   wr_bt   @ 18353152     524,288   [512][512] bf16 w_rank[:, :512]
//   rank_l  @ 18877440       2,048   [512] f32 w_rank[:, 512]
//   bias2   @ 18879488       6,144   [1536] f32 b_ih + (bhh for r,z gates)
//   keys    @ 18885632   8,404,992   [8][513][512] u32 scatter-max (xbf 2MB aliases here;
//                                    memset of keys is enqueued AFTER k_gemm_xw)
//   base_v  @ 27290624   8,388,608   [8][512][512] f32
//   nx      @ 35679232 134,217,728   [131072][512] bf16

#define HH 256
#define NNODE 512
#define PLEN 64

typedef __attribute__((ext_vector_type(8))) short short8;
typedef __attribute__((ext_vector_type(4))) float f32x4;
typedef unsigned short ushort_t;
typedef __attribute__((address_space(1))) const void* gas_t;
typedef __attribute__((address_space(3))) void* las_t;

__device__ __forceinline__ f32x4 mfma16(short8 a, short8 b, f32x4 c) {
    return __builtin_amdgcn_mfma_f32_16x16x32_bf16(a, b, c, 0, 0, 0);
}
__device__ __forceinline__ ushort_t f2bf(float f) {
    unsigned u = __float_as_uint(f);
    u += 0x7fffu + ((u >> 16) & 1u);
    return (ushort_t)(u >> 16);
}
__device__ __forceinline__ float bf2f(ushort_t s) {
    return __uint_as_float(((unsigned)s) << 16);
}
__device__ __forceinline__ float sigm(float x) {
    return __builtin_amdgcn_rcpf(1.f + __expf(-x));
}
__device__ __forceinline__ float tanh_(float x) {
    return 1.f - 2.f * __builtin_amdgcn_rcpf(__expf(2.f * x) + 1.f);
}
__device__ __forceinline__ unsigned fkey(float f) {
    unsigned u = __float_as_uint(f);
    return (u & 0x80000000u) ? ~u : (u | 0x80000000u);
}
__device__ __forceinline__ float fdec(unsigned k) {
    unsigned u = (k & 0x80000000u) ? (k ^ 0x80000000u) : ~k;
    return __uint_as_float(u);
}

// ---------------- embedding token max-pool ----------------
__global__ void k_embed(const int* __restrict__ nodes, const float* __restrict__ emb,
                        float* __restrict__ x, ushort_t* __restrict__ xbf)
{
    const int bn = blockIdx.x, h = threadIdx.x;
    const int* nd = nodes + bn * 8;
    float m = -3.4e38f;
#pragma unroll
    for (int k = 0; k < 8; ++k)
        m = fmaxf(m, emb[(size_t)nd[k] * HH + h]);
    x[(size_t)bn * HH + h] = m;
    xbf[(size_t)bn * HH + h] = f2bf(m);
}

// ---------------- pack weights ----------------
__global__ void k_pack(const float* __restrict__ wf_ih, const float* __restrict__ wf_hh,
                       const float* __restrict__ bf_ih, const float* __restrict__ bf_hh,
                       const float* __restrict__ wb_ih, const float* __restrict__ wb_hh,
                       const float* __restrict__ bb_ih, const float* __restrict__ bb_hh,
                       const float* __restrict__ w_rank,
                       ushort_t* __restrict__ whhp, ushort_t* __restrict__ wih_bt,
                       ushort_t* __restrict__ wr_bt, float* __restrict__ rank_l,
                       float* __restrict__ bias2,
                       ushort_t* __restrict__ xwRZ, ushort_t* __restrict__ xwN)
{
    int i = blockIdx.x * 256 + threadIdx.x;
    if (i < 393216) {
        // chunk c = ((dir*16 + w)*8 + kt)*3 + g; lane l elem e:
        // whhp <- whh[g*256 + w*16 + (l&15)][kt*32 + (l>>4)*8 + e]
        const int e = i & 7, l = (i >> 3) & 63;
        int c = i >> 9;
        const int g = c % 3; c /= 3;
        const int kt = c & 7; c >>= 3;
        const int w2 = c & 15;
        const int dir = c >> 4;
        const float* whh = dir ? wb_hh : wf_hh;
        whhp[i] = f2bf(whh[(g * 256 + w2 * 16 + (l & 15)) * 256 +
                           kt * 32 + (l >> 4) * 8 + e]);
        return;
    }
    i -= 393216;
    if (i < 393216) {   // wih_bt [1536][256]
        const int n = i >> 8, k = i & 255;
        const float* wih = (n < 768) ? wf_ih : wb_ih;
        wih_bt[i] = f2bf(wih[(n % 768) * 256 + k]);
        return;
    }
    i -= 393216;
    if (i < 262144) { wr_bt[i] = f2bf(w_rank[(i >> 9) * 513 + (i & 511)]); return; }
    i -= 262144;
    if (i < 512) { rank_l[i] = w_rank[i * 513 + 512]; return; }
    i -= 512;
    if (i < 1536) {
        const int c = i;
        const int dir = c >= 768;
        const int cd = c - dir * 768;
        const int g = cd >> 8, cc = cd & 255;
        const float bi = dir ? bb_ih[cd] : bf_ih[cd];
        const float bh = (g < 2) ? (dir ? bb_hh[cd] : bf_hh[cd]) : 0.f;
        bias2[c] = bi + bh;
        const size_t ro = (size_t)(4096 * 2 + dir) * 256 + cc;   // padding row
        if (g < 2) xwRZ[ro * 2 + g] = f2bf(bi + bh);
        else       xwN[ro] = f2bf(bi + bh);
    }
}

// ---------------- GEMM mainloop (256 thr, 128x128, BK=64; A,Bt row-major [*][K]) ----
template<int KD>
__device__ __forceinline__ void gemm_loop(const ushort_t* __restrict__ A,
                                          const ushort_t* __restrict__ Bt,
                                          ushort_t* al, ushort_t* bl,
                                          int bm, int bn, f32x4 acc[4][4])
{
    const int tid = threadIdx.x, w = tid >> 6, l = tid & 63;
    const int lm = l & 15, lh = l >> 4;
    const int wm = w >> 1, wn = w & 1;
    const int lr = l >> 3, lc = (l & 7) * 8;
    for (int k0 = 0; k0 < KD; k0 += 64) {
#pragma unroll
        for (int i = 0; i < 4; ++i) {
            const int c = w * 4 + i;
            const ushort_t* ga = A + (size_t)(bm + c * 8 + lr) * KD + k0 + lc;
            const ushort_t* gb = Bt + (size_t)(bn + c * 8 + lr) * KD + k0 + lc;
            __builtin_amdgcn_global_load_lds((gas_t)ga, (las_t)(al + c * 512), 16, 0, 0);
            __builtin_amdgcn_global_load_lds((gas_t)gb, (las_t)(bl + c * 512), 16, 0, 0);
        }
        __syncthreads();
#pragma unroll
        for (int kt = 0; kt < 2; ++kt) {
            short8 af[4], bfr[4];
            const int ko = kt * 32 + lh * 8;
#pragma unroll
            for (int m = 0; m < 4; ++m)
                af[m] = *(const short8*)(al + (wm * 64 + m * 16 + lm) * 64 + ko);
#pragma unroll
            for (int n = 0; n < 4; ++n)
                bfr[n] = *(const short8*)(bl + (wn * 64 + n * 16 + lm) * 64 + ko);
#pragma unroll
            for (int m = 0; m < 4; ++m)
#pragma unroll
                for (int n = 0; n < 4; ++n)
                    acc[m][n] = mfma16(af[m], bfr[n], acc[m][n]);
        }
        __syncthreads();
    }
}

// ---------------- xw GEMM: [4096][256] @ [256][1536] + bias2 -> split planes ------
__global__ void __launch_bounds__(256, 2)
k_gemm_xw(const ushort_t* __restrict__ xbf, const ushort_t* __restrict__ wih_bt,
          const float* __restrict__ bias2,
          ushort_t* __restrict__ xwRZ, ushort_t* __restrict__ xwN)
{
    __shared__ __align__(16) ushort_t al[128 * 64], bl[128 * 64];
    f32x4 acc[4][4] = {};
    const int bm = blockIdx.y * 128, bn = blockIdx.x * 128;
    gemm_loop<256>(xbf, wih_bt, al, bl, bm, bn, acc);
    const int tid = threadIdx.x, w = tid >> 6, l = tid & 63;
    const int lm = l & 15, lh = l >> 4, wm = w >> 1, wn = w & 1;
#pragma unroll
    for (int m = 0; m < 4; ++m)
#pragma unroll
        for (int rr = 0; rr < 4; ++rr) {
            const int row = bm + wm * 64 + m * 16 + lh * 4 + rr;
#pragma unroll
            for (int n = 0; n < 4; ++n) {
                const int col = bn + wn * 64 + n * 16 + lm;
                const int dir = col >= 768;
                const int cd = col - dir * 768;
                const int g = cd >> 8, cc = cd & 255;
                const ushort_t v = f2bf(acc[m][n][rr] + bias2[col]);
                const size_t ro = (size_t)(row * 2 + dir) * 256 + cc;
                if (g < 2) xwRZ[ro * 2 + g] = v;
                else       xwN[ro] = v;
            }
        }
}

// ---------------- GRU scan core (16 waves) ----------------
// wave w owns gate-cols [w*16, w*16+16) of each of the 3 gates.
// Bf = 24 x short8 = 96 regs/lane (fits the 128-reg 1024-thread cap).
template<bool IS_BASE>
__device__ __forceinline__ void scan_run(int dir, int sg, int tid,
    const ushort_t* __restrict__ xwRZ, const ushort_t* __restrict__ xwN,
    const ushort_t* __restrict__ whhp, const float* __restrict__ bhh,
    ushort_t (*hl)[8192], const int* idr,
    ushort_t* __restrict__ nx, float* __restrict__ base_v)
{
    const int w = tid >> 6, l = tid & 63;
    const int lm = l & 15, lh = l >> 4;
    const int col = w * 16 + lm;
    const int nsteps = IS_BASE ? NNODE : PLEN;

    short8 Bf[8][3];
    {
        const ushort_t* wp = whhp + (size_t)(dir * 16 + w) * 12288 + l * 8;
#pragma unroll
        for (int kt = 0; kt < 8; ++kt)
#pragma unroll
            for (int g = 0; g < 3; ++g) {
                short8 v = *(const short8*)(wp + (kt * 3 + g) * 512);
                asm volatile("" : "+v"(v));   // pin: load once, no sink into loop
                Bf[kt][g] = v;
            }
    }
    const float bn_ = bhh[512 + col];

    __syncthreads();
    for (int i = tid; i < 4096; i += 1024) hl[0][i] = 0;
    __syncthreads();

    int cur = 0;
    for (int step = 0; step < nsteps; ++step) {
        const int t = dir ? (nsteps - 1 - step) : step;
        // per-ri gather: u32 {r|z} + u16 {n}  (6B/lane, hidden under MFMA)
        unsigned grz[4]; ushort_t gn[4];
#pragma unroll
        for (int ri = 0; ri < 4; ++ri) {
            const int sq = lh * 4 + ri;
            const int row = IS_BASE ? ((sq < 8) ? ((sq << 9) + t) : 4096)
                                    : idr[(sq << 6) + t];
            const size_t ro = (size_t)(row * 2 + dir) * 256 + col;
            grz[ri] = *(const unsigned*)(xwRZ + ro * 2);
            gn[ri] = xwN[ro];
        }
        // gates = h @ whh^T: M=16 seqs, 16 cols x 3 gates, K=256
        f32x4 acc[3] = {};
        const char* hb = (const char*)hl[cur];
#pragma unroll
        for (int kt = 0; kt < 8; ++kt) {
            const short8 a = *(const short8*)(hb + lm * 512 +
                ((kt * 64 + lh * 16) ^ ((lm & 7) << 4)));
            acc[0] = mfma16(a, Bf[kt][0], acc[0]);
            acc[1] = mfma16(a, Bf[kt][1], acc[1]);
            acc[2] = mfma16(a, Bf[kt][2], acc[2]);
        }
        ushort_t* hn_ = hl[cur ^ 1];
#pragma unroll
        for (int ri = 0; ri < 4; ++ri) {
            const int sq = lh * 4 + ri;
            const int hoff = sq * 512 + ((col * 2) ^ ((sq & 7) << 4));
            const float hov = bf2f(*(const ushort_t*)(hb + hoff));
            const float xr = bf2f((ushort_t)(grz[ri] & 0xffffu));
            const float xz = bf2f((ushort_t)(grz[ri] >> 16));
            const float xn = bf2f(gn[ri]);
            const float rr = sigm(acc[0][ri] + xr);
            const float zz = sigm(acc[1][ri] + xz);
            const float nn = tanh_(xn + rr * (acc[2][ri] + bn_));
            const float h = (1.f - zz) * nn + zz * hov;
            const ushort_t h16 = f2bf(h);
            *(ushort_t*)((char*)hn_ + hoff) = h16;
            if (IS_BASE) {
                if (sq < 8)
                    base_v[((size_t)(sq * NNODE + t)) * 512 + dir * 256 + col] = h;
            } else {
                nx[((size_t)((sg * 16 + sq) * PLEN + t)) * 512 + dir * 256 + col] = h16;
            }
        }
        __syncthreads();
        cur ^= 1;
    }
}

// ---------------- fused: blocks 0,1 = base GRU; 2..129 = path scan + rank GEMM ----
// LDS = 84KB: forces 1 block/CU (4 waves/SIMD for 16 waves -> 128-reg budget,
// which the 96-reg Bf design fits).
__global__ void __launch_bounds__(1024, 1)
k_scan(const int* __restrict__ paths,
       const ushort_t* __restrict__ xwRZ, const ushort_t* __restrict__ xwN,
       const ushort_t* __restrict__ whhp,
       const float* __restrict__ bf_hh, const float* __restrict__ bb_hh,
       const ushort_t* __restrict__ wr_bt, const float* __restrict__ b_rank,
       const float* __restrict__ rank_l,
       ushort_t* __restrict__ nx, float* __restrict__ base_v,
       unsigned* __restrict__ keys)
{
    __shared__ __align__(16) ushort_t hl[2][8192];           // 32 KB (scan uses 16)
    __shared__ __align__(16) ushort_t al[12288], bl[12288];  // 48 KB (rank uses 32)
    __shared__ int idr[1024];                                // 4 KB -> 84 KB total
    const int tid = threadIdx.x;
    const int w = tid >> 6, l = tid & 63;
    const int lm = l & 15, lh = l >> 4;

    if (blockIdx.x < 2) {
        scan_run<true>((int)blockIdx.x, 0, tid, xwRZ, xwN, whhp,
                       blockIdx.x ? bb_hh : bf_hh, hl, nullptr, nx, base_v);
        return;
    }
    const int sg = (int)blockIdx.x - 2;
    {
        const int s = sg * 16 + (tid >> 6), t = tid & 63;
        const int id = paths[(s << 6) + t];
        idr[tid] = (id < NNODE) ? (((s >> 8) << 9) + id) : 4096;
    }
    scan_run<false>(0, sg, tid, xwRZ, xwN, whhp, bf_hh, hl, idr, nx, base_v);
    scan_run<false>(1, sg, tid, xwRZ, xwN, whhp, bb_hh, hl, idr, nx, base_v);

    // ---- rank phase: own 1024 nx rows @ wr^T, 32 jobs of 128x128 tiles, K=512 ----
    __threadfence_block();
    __syncthreads();
    const int wm = w >> 2, wn = w & 3;   // 4x4 waves, wave tile 32x32
#pragma unroll 1
    for (int job = 0; job < 32; ++job) {
        const int mt = job >> 2, ntile = job & 3;
        const size_t ar0 = (size_t)sg * 1024 + mt * 128;
        const int n0 = ntile * 128;
        f32x4 racc[2][2] = {};
        for (int k0 = 0; k0 < 512; k0 += 64) {
            {
                const int row = tid >> 3, j = tid & 7;
                const int jp = j ^ (row & 7);   // pre-swizzled source (both-sides rule)
                __builtin_amdgcn_global_load_lds(
                    (gas_t)(nx + (ar0 + row) * 512 + k0 + jp * 8),
                    (las_t)(al + tid * 8), 16, 0, 0);
                __builtin_amdgcn_global_load_lds(
                    (gas_t)(wr_bt + (size_t)(n0 + row) * 512 + k0 + jp * 8),
                    (las_t)(bl + tid * 8), 16, 0, 0);
            }
            __syncthreads();
#pragma unroll
            for (int kt = 0; kt < 2; ++kt) {
                short8 av[2], bv[2];
#pragma unroll
                for (int m = 0; m < 2; ++m) {
                    const int r = wm * 32 + m * 16 + lm;
                    av[m] = *(const short8*)((const char*)al + r * 128 +
                            ((kt * 64 + lh * 16) ^ ((r & 7) << 4)));
                }
#pragma unroll
                for (int n = 0; n < 2; ++n) {
                    const int r = wn * 32 + n * 16 + lm;
                    bv[n] = *(const short8*)((const char*)bl + r * 128 +
                            ((kt * 64 + lh * 16) ^ ((r & 7) << 4)));
                }
#pragma unroll
                for (int m = 0; m < 2; ++m)
#pragma unroll
                    for (int n = 0; n < 2; ++n)
                        racc[m][n] = mfma16(av[m], bv[n], racc[m][n]);
            }
            __syncthreads();
        }
#pragma unroll
        for (int m = 0; m < 2; ++m)
#pragma unroll
            for (int rr = 0; rr < 4; ++rr) {
                const size_t grow = ar0 + wm * 32 + m * 16 + lh * 4 + rr;
                const int id = paths[grow];
                const float rv = __builtin_amdgcn_rcpf((float)(((grow >> 6) & 255) + 1));
                unsigned* kp = keys + (((grow >> 14) * 513 + id) << 9);
#pragma unroll
                for (int n = 0; n < 2; ++n) {
                    const int col = n0 + wn * 32 + n * 16 + lm;
                    const float v = racc[m][n][rr] + b_rank[col] + rank_l[col] * rv;
                    if (id < NNODE) {
                        const unsigned key = fkey(v);
                        if (key > kp[col]) atomicMax(kp + col, key);
                    }
                }
            }
    }
}

// ---------------- merge: v = has ? vmax : transit(x);  all_v = base_v + v ----------------
__global__ void k_merge(const unsigned* __restrict__ keys, const float* __restrict__ base_v,
                        const float* __restrict__ x, const float* __restrict__ w_transit,
                        const float* __restrict__ b_transit, float* __restrict__ out0)
{
    const int blk = blockIdx.x;
    const int b = blk >> 9, n = blk & 511;
    const int tid = threadIdx.x;
#pragma unroll
    for (int h = 0; h < 2; ++h) {
        const int o = tid + h * 256;
        const unsigned k = keys[((size_t)(b * 513 + n)) * 512 + o];
        float v;
        if (k) {
            v = fdec(k);
        } else {
            float a = b_transit[o];
            const float* wt = w_transit + o * HH;
            const float* xr = x + ((size_t)(b * NNODE + n)) * HH;
            for (int i = 0; i < HH; ++i) a += xr[i] * wt[i];
            v = a;
        }
        const size_t oi = ((size_t)(b * NNODE + n)) * 512 + o;
        out0[oi] = base_v[oi] + v;
    }
}

// ---------------- last_state: rowmax over nodes, then @ w_h.T + b_h ----------------
__global__ void k_last(const float* __restrict__ out0, const float* __restrict__ w_h,
                       const float* __restrict__ b_h, float* __restrict__ out1)
{
    __shared__ float m[512];
    const int b = blockIdx.x, tid = threadIdx.x;
#pragma unroll
    for (int h = 0; h < 2; ++h) {
        const int o = tid + h * 256;
        float mm = -3.4e38f;
        for (int n = 0; n < NNODE; ++n)
            mm = fmaxf(mm, out0[((size_t)(b * NNODE + n)) * 512 + o]);
        m[o] = mm;
    }
    __syncthreads();
    float a = b_h[tid];
    const float* wr = w_h + tid * 512;
    for (int j = 0; j < 512; ++j) a += m[j] * wr[j];
    out1[b * HH + tid] = a;
}

extern "C" void kernel_launch(void* const* d_in, const int* in_sizes, int n_in,
                              void* d_out, int out_size, void* d_ws, size_t ws_size,
                              hipStream_t stream)
{
    (void)in_sizes; (void)n_in; (void)out_size; (void)ws_size;
    const int* nodes = (const int*)d_in[0];
    const int* paths = (const int*)d_in[1];
    const float* emb = (const float*)d_in[2];
    const float* wf_ih = (const float*)d_in[3];
    const float* wf_hh = (const float*)d_in[4];
    const float* bf_ih = (const float*)d_in[5];
    const float* bf_hh = (const float*)d_in[6];
    const float* wb_ih = (const float*)d_in[7];
    const float* wb_hh = (const float*)d_in[8];
    const float* bb_ih = (const float*)d_in[9];
    const float* bb_hh = (const float*)d_in[10];
    const float* w_transit = (const float*)d_in[11];
    const float* b_transit = (const float*)d_in[12];
    const float* w_rank = (const float*)d_in[13];
    const float* b_rank = (const float*)d_in[14];
    const float* w_h = (const float*)d_in[15];
    const float* b_h = (const float*)d_in[16];

    char* ws = (char*)d_ws;
    float* x = (float*)(ws);
    ushort_t* xwRZ = (ushort_t*)(ws + 4194304);
    ushort_t* xwN = (ushort_t*)(ws + 12584960);
    ushort_t* whhp = (ushort_t*)(ws + 16780288);
    ushort_t* wih_bt = (ushort_t*)(ws + 17566720);
    ushort_t* wr_bt = (ushort_t*)(ws + 18353152);
    float* rank_l = (float*)(ws + 18877440);
    float* bias2 = (float*)(ws + 18879488);
    unsigned* keys = (unsigned*)(ws + 18885632);
    ushort_t* xbf = (ushort_t*)(ws + 18885632);   // aliases keys (dead before memset)
    float* base_v = (float*)(ws + 27290624);
    ushort_t* nx = (ushort_t*)(ws + 35679232);

    float* out0 = (float*)d_out;
    float* out1 = out0 + 2097152;

    k_embed<<<4096, 256, 0, stream>>>(nodes, emb, x, xbf);
    k_pack<<<4104, 256, 0, stream>>>(wf_ih, wf_hh, bf_ih, bf_hh, wb_ih, wb_hh,
                                     bb_ih, bb_hh, w_rank,
                                     whhp, wih_bt, wr_bt, rank_l, bias2, xwRZ, xwN);
    k_gemm_xw<<<dim3(12, 32), 256, 0, stream>>>(xbf, wih_bt, bias2, xwRZ, xwN);
    hipMemsetAsync(keys, 0, 8404992, stream);   // after k_gemm_xw: xbf alias is dead now
    k_scan<<<130, 1024, 0, stream>>>(paths, xwRZ, xwN, whhp, bf_hh, bb_hh, wr_bt,
                                     b_rank, rank_l, nx, base_v, keys);
    k_merge<<<4096, 256, 0, stream>>>(keys, base_v, x, w_transit, b_transit, out0);
    k_last<<<8, 256, 0, stream>>>(out0, w_h, b_h, out1);
}

// Round 9
// 1886.935 us; speedup vs baseline: 1.0815x; 1.0815x over previous
//
#include <hip/hip_runtime.h>

// PathEncoder: B=8, N_NODE=512, N_TOK=8, N_PATHS=256, PATH_LEN=64, VOCAB=50000, H=256
// Round 9: three-tier weight storage for the GRU scan. Allocator law (measured
// r1-r8): VGPR budget = 65536/threads, LDS-blind -> full register residency of
// the 384KB/dir whh is impossible. Split per (dir,wave)=48 B-frags:
//   REG   q0..11  (kt0,kt1)          48 regs, pinned
//   LDS   q12..27 (kt2,kt3,kt4 g0/g1) 131KB, loaded once/dir, ds_read per step
//   STREAM q28..47 (kt4 g2, kt5..7)  164KB/step from L2 (vs 384KB spill before)
// 512 thr / 8 waves (reliable 128-reg budget). Rank phase reuses the weight LDS.
//
// ws layout (bytes): identical to round 5.
//   x       @ 0          4,194,304   [4096][256] f32
//   xbf     @ 4194304    2,097,152   [4096][256] bf16
//   xw3     @ 6291456   12,585,984   [4097]x1536 bf16 packed: dir*768 + w*96 + lm*6 + g*2 + n
//   whhp    @ 18877440     786,432   packed whh bf16 B-frags, chunk (dir*8+w)*48+q
//   wih_bt  @ 19663872     786,432   [1536][256] bf16 concat(wf_ih, wb_ih)
//   wr_bt   @ 20450304     524,288   [512][512] bf16 w_rank[:, :512]
//   rank_l  @ 20974592       2,048   [512] f32 w_rank[:, 512]
//   bias2   @ 20976640       6,144   [1536] f32 b_ih + (bhh for r,z gates)
//   keys    @ 20982784   8,404,992   [8][513][512] u32 scatter-max
//   base_v  @ 29387776   8,388,608   [8][512][512] f32
//   nx      @ 37776384 134,217,728   [131072][512] bf16

#define HH 256
#define NNODE 512
#define PLEN 64

typedef __attribute__((ext_vector_type(8))) short short8;
typedef __attribute__((ext_vector_type(4))) float f32x4;
typedef unsigned short ushort_t;
typedef __attribute__((address_space(1))) const void* gas_t;
typedef __attribute__((address_space(3))) void* las_t;

__device__ __forceinline__ f32x4 mfma16(short8 a, short8 b, f32x4 c) {
    return __builtin_amdgcn_mfma_f32_16x16x32_bf16(a, b, c, 0, 0, 0);
}
__device__ __forceinline__ ushort_t f2bf(float f) {
    unsigned u = __float_as_uint(f);
    u += 0x7fffu + ((u >> 16) & 1u);
    return (ushort_t)(u >> 16);
}
__device__ __forceinline__ float bf2f(ushort_t s) {
    return __uint_as_float(((unsigned)s) << 16);
}
__device__ __forceinline__ float sigm(float x) {
    return __builtin_amdgcn_rcpf(1.f + __expf(-x));
}
__device__ __forceinline__ float tanh_(float x) {
    return 1.f - 2.f * __builtin_amdgcn_rcpf(__expf(2.f * x) + 1.f);
}
__device__ __forceinline__ unsigned fkey(float f) {
    unsigned u = __float_as_uint(f);
    return (u & 0x80000000u) ? ~u : (u | 0x80000000u);
}
__device__ __forceinline__ float fdec(unsigned k) {
    unsigned u = (k & 0x80000000u) ? (k ^ 0x80000000u) : ~k;
    return __uint_as_float(u);
}

// xw3 remap: original col c in [0,1536) -> packed element offset within a row.
// col within dir: g*256 + w*32 + 2*lm + n  ->  w*96 + lm*6 + g*2 + n
__device__ __forceinline__ int xw3_remap(int c) {
    const int dir = c >= 768;
    const int cd = c - dir * 768;
    const int g = cd >> 8, cc = cd & 255;
    const int w2 = cc >> 5, within = cc & 31;
    return dir * 768 + w2 * 96 + (within >> 1) * 6 + g * 2 + (within & 1);
}

// ---------------- embedding token max-pool ----------------
__global__ void k_embed(const int* __restrict__ nodes, const float* __restrict__ emb,
                        float* __restrict__ x, ushort_t* __restrict__ xbf)
{
    const int bn = blockIdx.x, h = threadIdx.x;
    const int* nd = nodes + bn * 8;
    float m = -3.4e38f;
#pragma unroll
    for (int k = 0; k < 8; ++k)
        m = fmaxf(m, emb[(size_t)nd[k] * HH + h]);
    x[(size_t)bn * HH + h] = m;
    xbf[(size_t)bn * HH + h] = f2bf(m);
}

// ---------------- pack weights ----------------
__global__ void k_pack(const float* __restrict__ wf_ih, const float* __restrict__ wf_hh,
                       const float* __restrict__ bf_ih, const float* __restrict__ bf_hh,
                       const float* __restrict__ wb_ih, const float* __restrict__ wb_hh,
                       const float* __restrict__ bb_ih, const float* __restrict__ bb_hh,
                       const float* __restrict__ w_rank,
                       ushort_t* __restrict__ whhp, ushort_t* __restrict__ wih_bt,
                       ushort_t* __restrict__ wr_bt, float* __restrict__ rank_l,
                       float* __restrict__ bias2, ushort_t* __restrict__ xw3)
{
    int i = blockIdx.x * 256 + threadIdx.x;
    if (i < 393216) {
        // chunk c = (dir*8 + w)*48 + q; q -> (kt,g,n) per three-tier order.
        const int e = i & 7, l = (i >> 3) & 63;
        const int c = i >> 9;
        const int q = c % 48;
        const int w2 = (c / 48) & 7;
        const int dir = c / 384;
        int kt, g;
        if (q < 12)      { kt = q / 6;            g = (q % 6) >> 1; }
        else if (q < 24) { kt = 2 + (q - 12) / 6; g = ((q - 12) % 6) >> 1; }
        else if (q < 28) { kt = 4;                g = (q - 24) >> 1; }
        else if (q < 30) { kt = 4;                g = 2; }
        else             { kt = 5 + (q - 30) / 6; g = ((q - 30) % 6) >> 1; }
        const int n = q & 1;
        const float* whh = dir ? wb_hh : wf_hh;
        whhp[i] = f2bf(whh[(g * 256 + w2 * 32 + 2 * (l & 15) + n) * 256 +
                           kt * 32 + (l >> 4) * 8 + e]);
        return;
    }
    i -= 393216;
    if (i < 393216) {   // wih_bt [1536][256]
        const int n = i >> 8, k = i & 255;
        const float* wih = (n < 768) ? wf_ih : wb_ih;
        wih_bt[i] = f2bf(wih[(n % 768) * 256 + k]);
        return;
    }
    i -= 393216;
    if (i < 262144) { wr_bt[i] = f2bf(w_rank[(i >> 9) * 513 + (i & 511)]); return; }
    i -= 262144;
    if (i < 512) { rank_l[i] = w_rank[i * 513 + 512]; return; }
    i -= 512;
    if (i < 1536) {
        const int c = i;
        const int dir = c >= 768;
        const int cd = c - dir * 768;
        const int g = cd >> 8;
        const float bi = dir ? bb_ih[cd] : bf_ih[cd];
        const float bh = (g < 2) ? (dir ? bb_hh[cd] : bf_hh[cd]) : 0.f;
        bias2[c] = bi + bh;
        xw3[(size_t)4096 * 1536 + xw3_remap(c)] = f2bf(bi + bh);  // padding row
    }
}

// ---------------- GEMM mainloop (256 thr, 128x128, BK=64; A,Bt row-major [*][K]) ----
template<int KD>
__device__ __forceinline__ void gemm_loop(const ushort_t* __restrict__ A,
                                          const ushort_t* __restrict__ Bt,
                                          ushort_t* al, ushort_t* bl,
                                          int bm, int bn, f32x4 acc[4][4])
{
    const int tid = threadIdx.x, w = tid >> 6, l = tid & 63;
    const int lm = l & 15, lh = l >> 4;
    const int wm = w >> 1, wn = w & 1;
    const int lr = l >> 3, lc = (l & 7) * 8;
    for (int k0 = 0; k0 < KD; k0 += 64) {
#pragma unroll
        for (int i = 0; i < 4; ++i) {
            const int c = w * 4 + i;
            const ushort_t* ga = A + (size_t)(bm + c * 8 + lr) * KD + k0 + lc;
            const ushort_t* gb = Bt + (size_t)(bn + c * 8 + lr) * KD + k0 + lc;
            __builtin_amdgcn_global_load_lds((gas_t)ga, (las_t)(al + c * 512), 16, 0, 0);
            __builtin_amdgcn_global_load_lds((gas_t)gb, (las_t)(bl + c * 512), 16, 0, 0);
        }
        __syncthreads();
#pragma unroll
        for (int kt = 0; kt < 2; ++kt) {
            short8 af[4], bfr[4];
            const int ko = kt * 32 + lh * 8;
#pragma unroll
            for (int m = 0; m < 4; ++m)
                af[m] = *(const short8*)(al + (wm * 64 + m * 16 + lm) * 64 + ko);
#pragma unroll
            for (int n = 0; n < 4; ++n)
                bfr[n] = *(const short8*)(bl + (wn * 64 + n * 16 + lm) * 64 + ko);
#pragma unroll
            for (int m = 0; m < 4; ++m)
#pragma unroll
                for (int n = 0; n < 4; ++n)
                    acc[m][n] = mfma16(af[m], bfr[n], acc[m][n]);
        }
        __syncthreads();
    }
}

// ---------------- xw GEMM: [4096][256] @ [256][1536] + bias2 -> packed bf16 ----------
__global__ void __launch_bounds__(256, 2)
k_gemm_xw(const ushort_t* __restrict__ xbf, const ushort_t* __restrict__ wih_bt,
          const float* __restrict__ bias2, ushort_t* __restrict__ xw3)
{
    __shared__ __align__(16) ushort_t al[128 * 64], bl[128 * 64];
    f32x4 acc[4][4] = {};
    const int bm = blockIdx.y * 128, bn = blockIdx.x * 128;
    gemm_loop<256>(xbf, wih_bt, al, bl, bm, bn, acc);
    const int tid = threadIdx.x, w = tid >> 6, l = tid & 63;
    const int lm = l & 15, lh = l >> 4, wm = w >> 1, wn = w & 1;
#pragma unroll
    for (int m = 0; m < 4; ++m)
#pragma unroll
        for (int rr = 0; rr < 4; ++rr) {
            const int row = bm + wm * 64 + m * 16 + lh * 4 + rr;
#pragma unroll
            for (int n = 0; n < 4; ++n) {
                const int col = bn + wn * 64 + n * 16 + lm;
                xw3[(size_t)row * 1536 + xw3_remap(col)] = f2bf(acc[m][n][rr] + bias2[col]);
            }
        }
}

// ---------------- GRU scan core (8 waves, three-tier weights) ----------------
// wave w owns hidden cols [w*32, w*32+32) as pairs (2lm, 2lm+1), all 3 gates.
template<bool IS_BASE>
__device__ __forceinline__ void scan_run(int dir, int sg, int tid,
    const ushort_t* __restrict__ xw3, const ushort_t* __restrict__ whhp,
    const float* __restrict__ bhh, ushort_t* __restrict__ wl,
    ushort_t (*hl)[4096], const int* idr,
    ushort_t* __restrict__ nx, float* __restrict__ base_v)
{
    const int w = tid >> 6, l = tid & 63;
    const int lm = l & 15, lh = l >> 4;
    const int nsteps = IS_BASE ? NNODE : PLEN;
    const ushort_t* wp = whhp + ((size_t)(dir * 8 + w) * 48) * 512 + l * 8;

    // REG tier: q0..11 (kt0, kt1), pinned against remat/sink
    short8 Breg[12];
#pragma unroll
    for (int q = 0; q < 12; ++q) {
        short8 v = *(const short8*)(wp + q * 512);
        asm volatile("" : "+v"(v));
        Breg[q] = v;
    }
    // LDS tier: q12..27 -> wl[(fi*8 + w)*512], fi = q-12 (lane offset auto = l*16B)
#pragma unroll
    for (int q = 12; q < 28; ++q)
        __builtin_amdgcn_global_load_lds((gas_t)(wp + q * 512),
            (las_t)(wl + ((q - 12) * 8 + w) * 512), 16, 0, 0);

    const float bn0 = bhh[512 + w * 32 + lm * 2];
    const float bn1 = bhh[512 + w * 32 + lm * 2 + 1];

    __syncthreads();                       // drains gload_lds (vmcnt) + joins waves
    for (int i = tid; i < 4096; i += 512) hl[0][i] = 0;
    __syncthreads();

    int cur = 0;
    for (int step = 0; step < nsteps; ++step) {
        const int t = dir ? (nsteps - 1 - step) : step;
        // xw gather: 12B per (lane, ri) = {r,z,n} x col-pair
        uint3 gv[4];
#pragma unroll
        for (int ri = 0; ri < 4; ++ri) {
            const int sq = lh * 4 + ri;
            const int row = IS_BASE ? ((sq < 8) ? ((sq << 9) + t) : 4096)
                                    : idr[(sq << 6) + t];
            gv[ri] = *(const uint3*)((const char*)xw3 +
                (size_t)row * 3072 + dir * 1536 + w * 192 + lm * 12);
        }
        // STREAM tier batch 1: q28..35 (kt4 g2 + kt5), hidden under kt0..3 MFMAs
        short8 st[8];
#pragma unroll
        for (int j = 0; j < 8; ++j) st[j] = *(const short8*)(wp + (28 + j) * 512);

        f32x4 acc[3][2] = {};
        const char* hb = (const char*)hl[cur];
        short8 af;
        // kt0, kt1: registers
#pragma unroll
        for (int kt = 0; kt < 2; ++kt) {
            af = *(const short8*)(hb + lm * 512 + ((kt * 64 + lh * 16) ^ ((lm & 7) << 4)));
#pragma unroll
            for (int j = 0; j < 6; ++j)
                acc[j >> 1][j & 1] = mfma16(af, Breg[kt * 6 + j], acc[j >> 1][j & 1]);
        }
        // kt2, kt3: LDS (fi 0..5, 6..11)
#pragma unroll
        for (int kt = 2; kt < 4; ++kt) {
            af = *(const short8*)(hb + lm * 512 + ((kt * 64 + lh * 16) ^ ((lm & 7) << 4)));
            const int fb = (kt - 2) * 6;
#pragma unroll
            for (int j = 0; j < 6; ++j) {
                const short8 b = *(const short8*)(wl + ((fb + j) * 8 + w) * 512 + l * 8);
                acc[j >> 1][j & 1] = mfma16(af, b, acc[j >> 1][j & 1]);
            }
        }
        // kt4: LDS fi12..15 (g0,g1) + stream st[0..1] (g2)
        af = *(const short8*)(hb + lm * 512 + ((4 * 64 + lh * 16) ^ ((lm & 7) << 4)));
#pragma unroll
        for (int j = 0; j < 4; ++j) {
            const short8 b = *(const short8*)(wl + ((12 + j) * 8 + w) * 512 + l * 8);
            acc[j >> 1][j & 1] = mfma16(af, b, acc[j >> 1][j & 1]);
        }
        acc[2][0] = mfma16(af, st[0], acc[2][0]);
        acc[2][1] = mfma16(af, st[1], acc[2][1]);
        // kt5: stream st[2..7]
        af = *(const short8*)(hb + lm * 512 + ((5 * 64 + lh * 16) ^ ((lm & 7) << 4)));
#pragma unroll
        for (int j = 0; j < 6; ++j)
            acc[j >> 1][j & 1] = mfma16(af, st[2 + j], acc[j >> 1][j & 1]);
        // kt6: reload st[2..7] from q36..41
#pragma unroll
        for (int j = 0; j < 6; ++j) st[2 + j] = *(const short8*)(wp + (36 + j) * 512);
        af = *(const short8*)(hb + lm * 512 + ((6 * 64 + lh * 16) ^ ((lm & 7) << 4)));
#pragma unroll
        for (int j = 0; j < 6; ++j)
            acc[j >> 1][j & 1] = mfma16(af, st[2 + j], acc[j >> 1][j & 1]);
        // kt7: reload st[2..7] from q42..47
#pragma unroll
        for (int j = 0; j < 6; ++j) st[2 + j] = *(const short8*)(wp + (42 + j) * 512);
        af = *(const short8*)(hb + lm * 512 + ((7 * 64 + lh * 16) ^ ((lm & 7) << 4)));
#pragma unroll
        for (int j = 0; j < 6; ++j)
            acc[j >> 1][j & 1] = mfma16(af, st[2 + j], acc[j >> 1][j & 1]);

        // gates + h update
        ushort_t* hn_ = hl[cur ^ 1];
#pragma unroll
        for (int ri = 0; ri < 4; ++ri) {
            const int sq = lh * 4 + ri;
            const unsigned hv = *(const unsigned*)(hb + sq * 512 +
                ((w * 64 + lm * 4) ^ ((sq & 7) << 4)));
            unsigned hpack = 0;
            float hs0 = 0.f, hs1 = 0.f;
#pragma unroll
            for (int n = 0; n < 2; ++n) {
                const float xr = bf2f((ushort_t)(n ? (gv[ri].x >> 16) : (gv[ri].x & 0xffffu)));
                const float xz = bf2f((ushort_t)(n ? (gv[ri].y >> 16) : (gv[ri].y & 0xffffu)));
                const float xn = bf2f((ushort_t)(n ? (gv[ri].z >> 16) : (gv[ri].z & 0xffffu)));
                const float hov = bf2f((ushort_t)(n ? (hv >> 16) : (hv & 0xffffu)));
                const float rr = sigm(acc[0][n][ri] + xr);
                const float zz = sigm(acc[1][n][ri] + xz);
                const float nn = tanh_(xn + rr * (acc[2][n][ri] + (n ? bn1 : bn0)));
                const float h = (1.f - zz) * nn + zz * hov;
                if (n) hs1 = h; else hs0 = h;
                hpack |= ((unsigned)f2bf(h)) << (n * 16);
            }
            *(unsigned*)((char*)hn_ + sq * 512 + ((w * 64 + lm * 4) ^ ((sq & 7) << 4))) = hpack;
            if (IS_BASE) {
                if (sq < 8)
                    *(float2*)(base_v + ((size_t)(sq * NNODE + t)) * 512 +
                               dir * 256 + w * 32 + lm * 2) = make_float2(hs0, hs1);
            } else {
                *(unsigned*)((char*)nx + (((size_t)((sg * 16 + sq) * PLEN + t)) * 512 +
                    dir * 256 + w * 32 + lm * 2) * 2) = hpack;
            }
        }
        __syncthreads();
        cur ^= 1;
    }
}

// ---------------- fused: blocks 0,1 = base GRU; 2..129 = path scan + rank GEMM ----
__global__ void __launch_bounds__(512)
k_scan(const int* __restrict__ paths, const ushort_t* __restrict__ xw3,
       const ushort_t* __restrict__ whhp,
       const float* __restrict__ bf_hh, const float* __restrict__ bb_hh,
       const ushort_t* __restrict__ wr_bt, const float* __restrict__ b_rank,
       const float* __restrict__ rank_l,
       ushort_t* __restrict__ nx, float* __restrict__ base_v,
       unsigned* __restrict__ keys)
{
    __shared__ __align__(16) ushort_t wl[65536];    // 128KB: weights (scan) / al,bl (rank)
    __shared__ __align__(16) ushort_t hl[2][4096];  // 16KB h double-buffer
    __shared__ int idr[1024];                       // 4KB -> 151.5KB total (1 block/CU)
    const int tid = threadIdx.x;
    const int w = tid >> 6, l = tid & 63;
    const int lm = l & 15, lh = l >> 4;

    if (blockIdx.x < 2) {
        scan_run<true>((int)blockIdx.x, 0, tid, xw3, whhp,
                       blockIdx.x ? bb_hh : bf_hh, wl, hl, nullptr, nx, base_v);
        return;
    }
    const int sg = (int)blockIdx.x - 2;
    for (int i = tid; i < 1024; i += 512) {
        const int s = sg * 16 + (i >> 6), t = i & 63;
        const int id = paths[(s << 6) + t];
        idr[i] = (id < NNODE) ? (((s >> 8) << 9) + id) : 4096;
    }
    scan_run<false>(0, sg, tid, xw3, whhp, bf_hh, wl, hl, idr, nx, base_v);
    scan_run<false>(1, sg, tid, xw3, whhp, bb_hh, wl, hl, idr, nx, base_v);

    // ---- rank phase: own 1024 nx rows @ wr^T, 32 jobs of 128x128 tiles, K=512 ----
    __threadfence_block();
    __syncthreads();
    ushort_t* al = wl;                // weights dead; reuse as GEMM staging
    ushort_t* bl = wl + 8192;
    const int wm = w >> 2, wn = w & 3;   // wave tile 64x32
#pragma unroll 1
    for (int job = 0; job < 32; ++job) {
        const int mt = job >> 2, ntile = job & 3;
        const size_t ar0 = (size_t)sg * 1024 + mt * 128;
        const int n0 = ntile * 128;
        f32x4 racc[4][2] = {};
        for (int k0 = 0; k0 < 512; k0 += 64) {
#pragma unroll
            for (int i = 0; i < 2; ++i) {
                const int c = w * 128 + i * 64 + l;
                const int row = c >> 3, j = c & 7;
                const int jp = j ^ (row & 7);   // pre-swizzled source (both-sides rule)
                __builtin_amdgcn_global_load_lds(
                    (gas_t)(nx + (ar0 + row) * 512 + k0 + jp * 8),
                    (las_t)(al + c * 8), 16, 0, 0);
                __builtin_amdgcn_global_load_lds(
                    (gas_t)(wr_bt + (size_t)(n0 + row) * 512 + k0 + jp * 8),
                    (las_t)(bl + c * 8), 16, 0, 0);
            }
            __syncthreads();
#pragma unroll
            for (int kt = 0; kt < 2; ++kt) {
                short8 av[4], bv[2];
#pragma unroll
                for (int m = 0; m < 4; ++m) {
                    const int r = wm * 64 + m * 16 + lm;
                    av[m] = *(const short8*)((const char*)al + r * 128 +
                            ((kt * 64 + lh * 16) ^ ((r & 7) << 4)));
                }
#pragma unroll
                for (int n = 0; n < 2; ++n) {
                    const int r = wn * 32 + n * 16 + lm;
                    bv[n] = *(const short8*)((const char*)bl + r * 128 +
                            ((kt * 64 + lh * 16) ^ ((r & 7) << 4)));
                }
#pragma unroll
                for (int m = 0; m < 4; ++m)
#pragma unroll
                    for (int n = 0; n < 2; ++n)
                        racc[m][n] = mfma16(av[m], bv[n], racc[m][n]);
            }
            __syncthreads();
        }
#pragma unroll
        for (int m = 0; m < 4; ++m)
#pragma unroll
            for (int rr = 0; rr < 4; ++rr) {
                const size_t grow = ar0 + wm * 64 + m * 16 + lh * 4 + rr;
                const int id = paths[grow];
                const float rv = __builtin_amdgcn_rcpf((float)(((grow >> 6) & 255) + 1));
                unsigned* kp = keys + (((grow >> 14) * 513 + id) << 9);
#pragma unroll
                for (int n = 0; n < 2; ++n) {
                    const int col = n0 + wn * 32 + n * 16 + lm;
                    const float v = racc[m][n][rr] + b_rank[col] + rank_l[col] * rv;
                    if (id < NNODE) {
                        const unsigned key = fkey(v);
                        if (key > kp[col]) atomicMax(kp + col, key);
                    }
                }
            }
    }
}

// ---------------- merge: v = has ? vmax : transit(x);  all_v = base_v + v ----------------
__global__ void k_merge(const unsigned* __restrict__ keys, const float* __restrict__ base_v,
                        const float* __restrict__ x, const float* __restrict__ w_transit,
                        const float* __restrict__ b_transit, float* __restrict__ out0)
{
    const int blk = blockIdx.x;
    const int b = blk >> 9, n = blk & 511;
    const int tid = threadIdx.x;
#pragma unroll
    for (int h = 0; h < 2; ++h) {
        const int o = tid + h * 256;
        const unsigned k = keys[((size_t)(b * 513 + n)) * 512 + o];
        float v;
        if (k) {
            v = fdec(k);
        } else {
            float a = b_transit[o];
            const float* wt = w_transit + o * HH;
            const float* xr = x + ((size_t)(b * NNODE + n)) * HH;
            for (int i = 0; i < HH; ++i) a += xr[i] * wt[i];
            v = a;
        }
        const size_t oi = ((size_t)(b * NNODE + n)) * 512 + o;
        out0[oi] = base_v[oi] + v;
    }
}

// ---------------- last_state: rowmax over nodes, then @ w_h.T + b_h ----------------
__global__ void k_last(const float* __restrict__ out0, const float* __restrict__ w_h,
                       const float* __restrict__ b_h, float* __restrict__ out1)
{
    __shared__ float m[512];
    const int b = blockIdx.x, tid = threadIdx.x;
#pragma unroll
    for (int h = 0; h < 2; ++h) {
        const int o = tid + h * 256;
        float mm = -3.4e38f;
        for (int n = 0; n < NNODE; ++n)
            mm = fmaxf(mm, out0[((size_t)(b * NNODE + n)) * 512 + o]);
        m[o] = mm;
    }
    __syncthreads();
    float a = b_h[tid];
    const float* wr = w_h + tid * 512;
    for (int j = 0; j < 512; ++j) a += m[j] * wr[j];
    out1[b * HH + tid] = a;
}

extern "C" void kernel_launch(void* const* d_in, const int* in_sizes, int n_in,
                              void* d_out, int out_size, void* d_ws, size_t ws_size,
                              hipStream_t stream)
{
    (void)in_sizes; (void)n_in; (void)out_size; (void)ws_size;
    const int* nodes = (const int*)d_in[0];
    const int* paths = (const int*)d_in[1];
    const float* emb = (const float*)d_in[2];
    const float* wf_ih = (const float*)d_in[3];
    const float* wf_hh = (const float*)d_in[4];
    const float* bf_ih = (const float*)d_in[5];
    const float* bf_hh = (const float*)d_in[6];
    const float* wb_ih = (const float*)d_in[7];
    const float* wb_hh = (const float*)d_in[8];
    const float* bb_ih = (const float*)d_in[9];
    const float* bb_hh = (const float*)d_in[10];
    const float* w_transit = (const float*)d_in[11];
    const float* b_transit = (const float*)d_in[12];
    const float* w_rank = (const float*)d_in[13];
    const float* b_rank = (const float*)d_in[14];
    const float* w_h = (const float*)d_in[15];
    const float* b_h = (const float*)d_in[16];

    char* ws = (char*)d_ws;
    float* x = (float*)(ws);
    ushort_t* xbf = (ushort_t*)(ws + 4194304);
    ushort_t* xw3 = (ushort_t*)(ws + 6291456);
    ushort_t* whhp = (ushort_t*)(ws + 18877440);
    ushort_t* wih_bt = (ushort_t*)(ws + 19663872);
    ushort_t* wr_bt = (ushort_t*)(ws + 20450304);
    float* rank_l = (float*)(ws + 20974592);
    float* bias2 = (float*)(ws + 20976640);
    unsigned* keys = (unsigned*)(ws + 20982784);
    float* base_v = (float*)(ws + 29387776);
    ushort_t* nx = (ushort_t*)(ws + 37776384);

    float* out0 = (float*)d_out;
    float* out1 = out0 + 2097152;

    hipMemsetAsync(keys, 0, 8404992, stream);
    k_embed<<<4096, 256, 0, stream>>>(nodes, emb, x, xbf);
    k_pack<<<4104, 256, 0, stream>>>(wf_ih, wf_hh, bf_ih, bf_hh, wb_ih, wb_hh,
                                     bb_ih, bb_hh, w_rank,
                                     whhp, wih_bt, wr_bt, rank_l, bias2, xw3);
    k_gemm_xw<<<dim3(12, 32), 256, 0, stream>>>(xbf, wih_bt, bias2, xw3);
    k_scan<<<130, 512, 0, stream>>>(paths, xw3, whhp, bf_hh, bb_hh, wr_bt,
                                    b_rank, rank_l, nx, base_v, keys);
    k_merge<<<4096, 256, 0, stream>>>(keys, base_v, x, w_transit, b_transit, out0);
    k_last<<<8, 256, 0, stream>>>(out0, w_h, b_h, out1);
}